// Round 2
// 78.573 us; speedup vs baseline: 1.0032x; 1.0032x over previous
//
#include <hip/hip_runtime.h>
#include <hip/hip_fp16.h>
#include <math.h>

#define N_GENES 20000
#define UNITS   10000
#define DEG     32
#define BATCH   128

// featT layout: [2][N_GENES][64] __half.
// Pass p holds batches p*64 .. p*64+63; each pass = 2.56 MB -> fits a 4 MiB
// per-XCD L2, so the random gene-row gather hits L2 instead of thrashing to
// Infinity Cache (the previous 5.12 MB working set could not fit).

// Kernel 1: featT[p][g][bh] = (half)|feature[b][g]|, 32x32 LDS tile.
__global__ __launch_bounds__(256) void transpose_abs_f16_kernel(
    const float* __restrict__ in, __half* __restrict__ out)
{
    __shared__ float tile[32][33];
    const int g0 = blockIdx.x * 32;
    const int b0 = blockIdx.y * 32;
    const int tx = threadIdx.x;   // 0..31
    const int ty = threadIdx.y;   // 0..7
#pragma unroll
    for (int i = 0; i < 32; i += 8)
        tile[ty + i][tx] = fabsf(in[(size_t)(b0 + ty + i) * N_GENES + (g0 + tx)]);
    __syncthreads();
    const int b  = b0 + tx;       // batch this lane writes (b0 % 32 == 0 -> single p per block)
    const int p  = b >> 6;
    const int bh = b & 63;
#pragma unroll
    for (int i = 0; i < 32; i += 8) {
        const int g = g0 + ty + i;
        out[((size_t)p * N_GENES + g) * 64 + bh] = __float2half(tile[tx][ty + i]);
    }
}

// Kernel 2: 8 units/block, 1250 blocks (exact), 4 waves.
// Lane decomposition (per wave): dpar = lane>>5 picks d-parity, (lane>>4)&1
// picks one of the wave's 2 units, bq = lane&15 picks the 8 B (4 batches)
// slice of the 128 B row. One dwordx2 per lane per iteration = 512 B per
// wave-instruction; 16 iterations per pass (vs 64 dword loads before).
// Two passes over batch halves keep the gather working set L2-resident.
__global__ __launch_bounds__(256) void gather_unit_v3(
    const __half2* __restrict__ featT,   // [2][N_GENES][32] half2
    const int*   __restrict__ ppi,
    const float* __restrict__ kernelw,
    const float* __restrict__ bias,
    float*       __restrict__ out)
{
    __shared__ int idx[8 * DEG];         // 256 indices = block size
    const int tid = threadIdx.x;
    const int u0  = blockIdx.x * 8;

    idx[tid] = ppi[(size_t)u0 * DEG + tid];
    __syncthreads();

    const int lane = tid & 63;
    const int w    = tid >> 6;                 // 0..3
    const int dpar = lane >> 5;                // 0/1: which d parity this half-wave sums
    const int ul   = w * 2 + ((lane >> 4) & 1); // local unit 0..7
    const int bq   = lane & 15;                // 8 B slice within the 128 B row
    const int u    = u0 + ul;
    const float kk = kernelw[u];
    const float cc = bias[u];
    const int* myidx = idx + ul * DEG;

#pragma unroll
    for (int p = 0; p < 2; ++p) {
        const uint2* fp = reinterpret_cast<const uint2*>(featT) + (size_t)p * N_GENES * 16;
        float acc0 = 0.f, acc1 = 0.f, acc2 = 0.f, acc3 = 0.f;
#pragma unroll
        for (int t = 0; t < 16; ++t) {
            const int d = 2 * t + dpar;
            const int g = myidx[d];                       // LDS broadcast (2 banks/wave)
            const uint2 raw = fp[(size_t)g * 16 + bq];    // global_load_dwordx2
            const float2 f0 = __half22float2(*reinterpret_cast<const __half2*>(&raw.x));
            const float2 f1 = __half22float2(*reinterpret_cast<const __half2*>(&raw.y));
            acc0 += f0.x; acc1 += f0.y; acc2 += f1.x; acc3 += f1.y;
        }
        // merge the two d-parities: lane l and l^32 hold the same (ul, bq)
        acc0 += __shfl_xor(acc0, 32, 64);
        acc1 += __shfl_xor(acc1, 32, 64);
        acc2 += __shfl_xor(acc2, 32, 64);
        acc3 += __shfl_xor(acc3, 32, 64);

        if (dpar == 0) {
            const int bbase = p * 64 + bq * 4;
            const float h0 = acc0 * kk + cc;
            const float h1 = acc1 * kk + cc;
            const float h2 = acc2 * kk + cc;
            const float h3 = acc3 * kk + cc;
            // tanh(h) = 1 - 2/(exp(2h)+1)
            out[(size_t)(bbase + 0) * UNITS + u] = 1.f - 2.f / (__expf(2.f * h0) + 1.f);
            out[(size_t)(bbase + 1) * UNITS + u] = 1.f - 2.f / (__expf(2.f * h1) + 1.f);
            out[(size_t)(bbase + 2) * UNITS + u] = 1.f - 2.f / (__expf(2.f * h2) + 1.f);
            out[(size_t)(bbase + 3) * UNITS + u] = 1.f - 2.f / (__expf(2.f * h3) + 1.f);
        }
    }
}

extern "C" void kernel_launch(void* const* d_in, const int* in_sizes, int n_in,
                              void* d_out, int out_size, void* d_ws, size_t ws_size,
                              hipStream_t stream) {
    const float* feature = (const float*)d_in[0];
    const int*   ppi     = (const int*)d_in[1];
    const float* kernelw = (const float*)d_in[2];
    const float* bias    = (const float*)d_in[3];
    float* out   = (float*)d_out;
    __half* featT = (__half*)d_ws;                 // 2*20000*64*2 = 5.12 MB

    dim3 g1(N_GENES / 32, BATCH / 32);
    dim3 b1(32, 8);
    transpose_abs_f16_kernel<<<g1, b1, 0, stream>>>(feature, featT);

    gather_unit_v3<<<UNITS / 8, 256, 0, stream>>>(
        (const __half2*)featT, ppi, kernelw, bias, out);
}